// Round 7
// baseline (2674.214 us; speedup 1.0000x reference)
//
#include <hip/hip_runtime.h>
#include <math.h>

#define Bn 128
#define Tn 512
#define Dn 32
#define Hn 128
#define Gn 512   // 4*H
#define Ln 3

// LDS-only barrier: does NOT drain vmcnt.
#define BAR_LDS() asm volatile("s_waitcnt lgkmcnt(0)\n\ts_barrier" ::: "memory")

// Opaque-origin pin: an asm-produced value cannot be rematerialized by
// re-loading, so the allocator must keep it in VGPRs (or visibly spill).
#define KEEP4(q) asm volatile("" : "+v"(q.x), "+v"(q.y), "+v"(q.z), "+v"(q.w))

// ---------------------------------------------------------------------------
// GEMM: pre[M, 512] = A_chunk[M, K] * W[512, K]^T + (b_ih + b_hh)
// ---------------------------------------------------------------------------
__global__ __launch_bounds__(256) void gemm_pre(
    const float* __restrict__ A, int K, int rowStrideB, int t0, int tlog,
    const float* __restrict__ W,
    const float* __restrict__ bi, const float* __restrict__ bh,
    float* __restrict__ C)
{
    __shared__ __align__(16) float As[8][128];
    __shared__ __align__(16) float Bs[8][128];
    const int tid  = threadIdx.x;
    const int row0 = blockIdx.x * 128;
    const int col0 = blockIdx.y * 128;
    const int ty = tid >> 4, tx = tid & 15;
    const int lr = tid >> 1, lk = (tid & 1) * 4;
    const int tmask = (1 << tlog) - 1;

    float acc[8][8];
    #pragma unroll
    for (int i = 0; i < 8; i++)
        #pragma unroll
        for (int j = 0; j < 8; j++) acc[i][j] = 0.f;

    for (int k0 = 0; k0 < K; k0 += 8) {
        {
            int rg = row0 + lr;
            int b_idx = rg >> tlog;
            int tt = rg & tmask;
            const float* ap = A + (size_t)b_idx * rowStrideB +
                              (size_t)(t0 + tt) * K + (k0 + lk);
            float4 av = *(const float4*)ap;
            As[lk + 0][lr] = av.x; As[lk + 1][lr] = av.y;
            As[lk + 2][lr] = av.z; As[lk + 3][lr] = av.w;
            const float* wp = W + (size_t)(col0 + lr) * K + (k0 + lk);
            float4 wv = *(const float4*)wp;
            Bs[lk + 0][lr] = wv.x; Bs[lk + 1][lr] = wv.y;
            Bs[lk + 2][lr] = wv.z; Bs[lk + 3][lr] = wv.w;
        }
        __syncthreads();
        #pragma unroll
        for (int kk = 0; kk < 8; kk++) {
            float4 a0 = *(const float4*)&As[kk][ty * 8];
            float4 a1 = *(const float4*)&As[kk][ty * 8 + 4];
            float4 b0 = *(const float4*)&Bs[kk][tx * 8];
            float4 b1v = *(const float4*)&Bs[kk][tx * 8 + 4];
            float av[8] = {a0.x, a0.y, a0.z, a0.w, a1.x, a1.y, a1.z, a1.w};
            float bv[8] = {b0.x, b0.y, b0.z, b0.w, b1v.x, b1v.y, b1v.z, b1v.w};
            #pragma unroll
            for (int i = 0; i < 8; i++)
                #pragma unroll
                for (int j = 0; j < 8; j++) acc[i][j] += av[i] * bv[j];
        }
        __syncthreads();
    }
    #pragma unroll
    for (int i = 0; i < 8; i++) {
        int r = row0 + ty * 8 + i;
        #pragma unroll
        for (int j = 0; j < 8; j += 4) {
            int g = col0 + tx * 8 + j;
            float4 o;
            o.x = acc[i][j + 0] + bi[g + 0] + bh[g + 0];
            o.y = acc[i][j + 1] + bi[g + 1] + bh[g + 1];
            o.z = acc[i][j + 2] + bi[g + 2] + bh[g + 2];
            o.w = acc[i][j + 3] + bi[g + 3] + bh[g + 3];
            *(float4*)&C[(size_t)r * Gn + g] = o;
        }
    }
}

// ---------------------------------------------------------------------------
// LSTM scan v3. 256 threads/block, one block per batch item.
// Thread tid handles gates (tid, tid+256) of unit u = tid&127:
//   tid <128: i_u and g_u;  tid>=128: f_u and o_u.
// Each readlane broadcast of h_k feeds TWO fmas (shared SGPR).
// Weights pinned in VGPRs via opaque asm (non-rematerializable);
// waves_per_eu(1,1) gives the 512-VGPR budget (1 wave/SIMD).
// ---------------------------------------------------------------------------
__device__ __forceinline__ float bcast(float v, int l) {
    return __int_as_float(__builtin_amdgcn_readlane(__float_as_int(v), l));
}
__device__ __forceinline__ float sigm(float x) {
    return __builtin_amdgcn_rcpf(1.f + __expf(-x));
}
__device__ __forceinline__ float tanh_fast(float x) {
    return 1.f - 2.f * __builtin_amdgcn_rcpf(1.f + __expf(2.f * x));
}

// 4 k-steps: 4 readlanes, each feeding 2 fmas (gate A and gate B).
#define MACG(hh, base, qa, qb)                  \
    {                                           \
        float s0 = bcast(hh, (base) + 0);       \
        float s1 = bcast(hh, (base) + 1);       \
        float s2 = bcast(hh, (base) + 2);       \
        float s3 = bcast(hh, (base) + 3);       \
        aA0 = fmaf(s0, qa.x, aA0);              \
        aB0 = fmaf(s0, qb.x, aB0);              \
        aA1 = fmaf(s1, qa.y, aA1);              \
        aB1 = fmaf(s1, qb.y, aB1);              \
        aA0 = fmaf(s2, qa.z, aA0);              \
        aB0 = fmaf(s2, qb.z, aB0);              \
        aA1 = fmaf(s3, qa.w, aA1);              \
        aB1 = fmaf(s3, qb.w, aB1);              \
    }

__global__ __launch_bounds__(256)
__attribute__((amdgpu_waves_per_eu(1, 1)))
void lstm_scan(
    const float* __restrict__ pre,     // [B*TCH, 512]
    const float* __restrict__ w_hh,    // [512, 128] (this layer)
    float* __restrict__ hs,            // [B, T, H] layer output
    float* __restrict__ h_state, float* __restrict__ c_state,
    int t0, int TCH, int first)
{
    const int b    = blockIdx.x;
    const int tid  = threadIdx.x;
    const int lane = tid & 63;
    const int u    = tid & 127;        // hidden unit
    const int gA   = tid;              // i (tid<128) or f (tid>=128)
    const int gB   = tid + 256;        // g (tid<128) or o (tid>=128)

    __shared__ __align__(16) float  h_sh[Hn];
    __shared__ __align__(16) float2 ex_sh[Hn];   // {f, o} from upper half

    const float4* wpA = (const float4*)(w_hh + (size_t)gA * Hn);
    const float4* wpB = (const float4*)(w_hh + (size_t)gB * Hn);
    float4 qa0  = wpA[0],  qa1  = wpA[1],  qa2  = wpA[2],  qa3  = wpA[3];
    float4 qa4  = wpA[4],  qa5  = wpA[5],  qa6  = wpA[6],  qa7  = wpA[7];
    float4 qa8  = wpA[8],  qa9  = wpA[9],  qa10 = wpA[10], qa11 = wpA[11];
    float4 qa12 = wpA[12], qa13 = wpA[13], qa14 = wpA[14], qa15 = wpA[15];
    float4 qa16 = wpA[16], qa17 = wpA[17], qa18 = wpA[18], qa19 = wpA[19];
    float4 qa20 = wpA[20], qa21 = wpA[21], qa22 = wpA[22], qa23 = wpA[23];
    float4 qa24 = wpA[24], qa25 = wpA[25], qa26 = wpA[26], qa27 = wpA[27];
    float4 qa28 = wpA[28], qa29 = wpA[29], qa30 = wpA[30], qa31 = wpA[31];
    float4 qb0  = wpB[0],  qb1  = wpB[1],  qb2  = wpB[2],  qb3  = wpB[3];
    float4 qb4  = wpB[4],  qb5  = wpB[5],  qb6  = wpB[6],  qb7  = wpB[7];
    float4 qb8  = wpB[8],  qb9  = wpB[9],  qb10 = wpB[10], qb11 = wpB[11];
    float4 qb12 = wpB[12], qb13 = wpB[13], qb14 = wpB[14], qb15 = wpB[15];
    float4 qb16 = wpB[16], qb17 = wpB[17], qb18 = wpB[18], qb19 = wpB[19];
    float4 qb20 = wpB[20], qb21 = wpB[21], qb22 = wpB[22], qb23 = wpB[23];
    float4 qb24 = wpB[24], qb25 = wpB[25], qb26 = wpB[26], qb27 = wpB[27];
    float4 qb28 = wpB[28], qb29 = wpB[29], qb30 = wpB[30], qb31 = wpB[31];
    KEEP4(qa0);  KEEP4(qa1);  KEEP4(qa2);  KEEP4(qa3);
    KEEP4(qa4);  KEEP4(qa5);  KEEP4(qa6);  KEEP4(qa7);
    KEEP4(qa8);  KEEP4(qa9);  KEEP4(qa10); KEEP4(qa11);
    KEEP4(qa12); KEEP4(qa13); KEEP4(qa14); KEEP4(qa15);
    KEEP4(qa16); KEEP4(qa17); KEEP4(qa18); KEEP4(qa19);
    KEEP4(qa20); KEEP4(qa21); KEEP4(qa22); KEEP4(qa23);
    KEEP4(qa24); KEEP4(qa25); KEEP4(qa26); KEEP4(qa27);
    KEEP4(qa28); KEEP4(qa29); KEEP4(qa30); KEEP4(qa31);
    KEEP4(qb0);  KEEP4(qb1);  KEEP4(qb2);  KEEP4(qb3);
    KEEP4(qb4);  KEEP4(qb5);  KEEP4(qb6);  KEEP4(qb7);
    KEEP4(qb8);  KEEP4(qb9);  KEEP4(qb10); KEEP4(qb11);
    KEEP4(qb12); KEEP4(qb13); KEEP4(qb14); KEEP4(qb15);
    KEEP4(qb16); KEEP4(qb17); KEEP4(qb18); KEEP4(qb19);
    KEEP4(qb20); KEEP4(qb21); KEEP4(qb22); KEEP4(qb23);
    KEEP4(qb24); KEEP4(qb25); KEEP4(qb26); KEEP4(qb27);
    KEEP4(qb28); KEEP4(qb29); KEEP4(qb30); KEEP4(qb31);

    float h0, h1, cr;
    if (first) {
        h0 = 0.f; h1 = 0.f; cr = 0.f;
    } else {
        h0 = h_state[b * Hn + lane];
        h1 = h_state[b * Hn + 64 + lane];
        cr = c_state[b * Hn + u];
    }

    const float* ppA = pre + (size_t)b * TCH * Gn + gA;
    const float* ppB = pre + (size_t)b * TCH * Gn + gB;
    float* hsb = hs + ((size_t)b * Tn + t0) * Hn;

    float pvA0 = ppA[0], pvB0 = ppB[0];
    float pvA1 = (TCH > 1) ? ppA[Gn] : pvA0;
    float pvB1 = (TCH > 1) ? ppB[Gn] : pvB0;

    float hlast = 0.f;
    for (int t = 0; t < TCH; t++) {
        float pvA = pvA0, pvB = pvB0;
        pvA0 = pvA1; pvB0 = pvB1;
        int tn = (t + 2 < TCH) ? (t + 2) : (TCH - 1);
        pvA1 = ppA[(size_t)tn * Gn];
        pvB1 = ppB[(size_t)tn * Gn];

        float aA0 = 0.f, aA1 = 0.f, aB0 = 0.f, aB1 = 0.f;
        MACG(h0, 0,  qa0,  qb0)  MACG(h0, 4,  qa1,  qb1)
        MACG(h0, 8,  qa2,  qb2)  MACG(h0, 12, qa3,  qb3)
        MACG(h0, 16, qa4,  qb4)  MACG(h0, 20, qa5,  qb5)
        MACG(h0, 24, qa6,  qb6)  MACG(h0, 28, qa7,  qb7)
        MACG(h0, 32, qa8,  qb8)  MACG(h0, 36, qa9,  qb9)
        MACG(h0, 40, qa10, qb10) MACG(h0, 44, qa11, qb11)
        MACG(h0, 48, qa12, qb12) MACG(h0, 52, qa13, qb13)
        MACG(h0, 56, qa14, qb14) MACG(h0, 60, qa15, qb15)
        MACG(h1, 0,  qa16, qb16) MACG(h1, 4,  qa17, qb17)
        MACG(h1, 8,  qa18, qb18) MACG(h1, 12, qa19, qb19)
        MACG(h1, 16, qa20, qb20) MACG(h1, 20, qa21, qb21)
        MACG(h1, 24, qa22, qb22) MACG(h1, 28, qa23, qb23)
        MACG(h1, 32, qa24, qb24) MACG(h1, 36, qa25, qb25)
        MACG(h1, 40, qa26, qb26) MACG(h1, 44, qa27, qb27)
        MACG(h1, 48, qa28, qb28) MACG(h1, 52, qa29, qb29)
        MACG(h1, 56, qa30, qb30) MACG(h1, 60, qa31, qb31)
        float accA = (aA0 + aA1) + pvA;
        float accB = (aB0 + aB1) + pvB;

        if (tid >= 128) {                      // f, o (waves 2,3 — uniform)
            float fv = sigm(accA);
            float ov = sigm(accB);
            ex_sh[u] = make_float2(fv, ov);
        }
        float iv = sigm(accA);                 // valid for tid<128
        float gv = tanh_fast(accB);
        BAR_LDS();

        if (tid < 128) {                       // waves 0,1 — uniform
            float2 fo = ex_sh[u];
            cr = fo.x * cr + iv * gv;
            float hnew = fo.y * tanh_fast(cr);
            hlast = hnew;
            h_sh[u] = hnew;
            hsb[(size_t)t * Hn + u] = hnew;    // store stays in flight
        }
        BAR_LDS();

        h0 = h_sh[lane];
        h1 = h_sh[lane + 64];
    }

    if (tid < 128) {
        h_state[b * Hn + u] = hlast;
        c_state[b * Hn + u] = cr;
    }
}

// ---------------------------------------------------------------------------
// Attention pooling + MLP head. One block per batch item, 256 threads.
// ---------------------------------------------------------------------------
__global__ __launch_bounds__(256) void head_kernel(
    const float* __restrict__ hs,
    const float* __restrict__ w_attn, const float* __restrict__ b_attn,
    const float* __restrict__ w1, const float* __restrict__ b1,
    const float* __restrict__ w2, const float* __restrict__ b2,
    float* __restrict__ out)
{
    const int b = blockIdx.x;
    const int tid = threadIdx.x;
    __shared__ __align__(16) float wa_sh[Hn];
    __shared__ __align__(16) float sc[Tn];
    __shared__ __align__(16) float red[256];
    __shared__ __align__(16) float ctx_sh[Hn];
    __shared__ __align__(16) float h1_sh[64];

    if (tid < Hn) wa_sh[tid] = w_attn[tid];
    __syncthreads();

    const float* hb = hs + (size_t)b * Tn * Hn;

    for (int t = tid; t < Tn; t += 256) {
        const float4* hv = (const float4*)(hb + (size_t)t * Hn);
        const float4* wvv = (const float4*)wa_sh;
        float s = 0.f;
        #pragma unroll
        for (int k = 0; k < 32; k++) {
            float4 h4 = hv[k], w4 = wvv[k];
            s += h4.x * w4.x + h4.y * w4.y + h4.z * w4.z + h4.w * w4.w;
        }
        sc[t] = s + b_attn[0];
    }
    __syncthreads();

    float m = fmaxf(sc[tid], sc[tid + 256]);
    red[tid] = m; __syncthreads();
    for (int s_ = 128; s_ > 0; s_ >>= 1) {
        if (tid < s_) red[tid] = fmaxf(red[tid], red[tid + s_]);
        __syncthreads();
    }
    float mx = red[0];
    __syncthreads();
    float e0 = __expf(sc[tid] - mx), e1 = __expf(sc[tid + 256] - mx);
    sc[tid] = e0; sc[tid + 256] = e1;
    red[tid] = e0 + e1; __syncthreads();
    for (int s_ = 128; s_ > 0; s_ >>= 1) {
        if (tid < s_) red[tid] += red[tid + s_];
        __syncthreads();
    }
    float inv = 1.f / red[0];
    __syncthreads();

    {
        int jj = tid & 127, half = tid >> 7;
        float a = 0.f;
        for (int t = half * 256; t < half * 256 + 256; t++)
            a += sc[t] * hb[(size_t)t * Hn + jj];
        red[tid] = a;
        __syncthreads();
        if (tid < Hn) ctx_sh[tid] = (red[tid] + red[tid + Hn]) * inv;
        __syncthreads();
    }

    if (tid < 64) {
        const float4* wvv = (const float4*)(w1 + (size_t)tid * Hn);
        const float4* cv = (const float4*)ctx_sh;
        float s = 0.f;
        #pragma unroll
        for (int k = 0; k < 32; k++) {
            float4 a = wvv[k], c = cv[k];
            s += a.x * c.x + a.y * c.y + a.z * c.z + a.w * c.w;
        }
        h1_sh[tid] = fmaxf(s + b1[tid], 0.f);
    }
    __syncthreads();

    if (tid < 4) {
        float s = 0.f;
        const float* wvv = w2 + tid * 64;
        #pragma unroll
        for (int k = 0; k < 64; k++) s += wvv[k] * h1_sh[k];
        out[b * 4 + tid] = s + b2[tid];
    }
}

// ---------------------------------------------------------------------------
extern "C" void kernel_launch(void* const* d_in, const int* in_sizes, int n_in,
                              void* d_out, int out_size, void* d_ws, size_t ws_size,
                              hipStream_t stream)
{
    const float* x        = (const float*)d_in[0];
    const float* w_ih0    = (const float*)d_in[1];
    const float* w_ih_rest= (const float*)d_in[2];
    const float* w_hh     = (const float*)d_in[3];
    const float* b_ih     = (const float*)d_in[4];
    const float* b_hh     = (const float*)d_in[5];
    const float* w_attn   = (const float*)d_in[6];
    const float* b_attn   = (const float*)d_in[7];
    const float* w1       = (const float*)d_in[8];
    const float* b1       = (const float*)d_in[9];
    const float* w2       = (const float*)d_in[10];
    const float* b2       = (const float*)d_in[11];
    float* out = (float*)d_out;

    float* ws   = (float*)d_ws;
    float* hs   = ws;
    float* h_st = hs + (size_t)Bn * Tn * Hn;
    float* c_st = h_st + (size_t)Bn * Hn;
    float* pre  = c_st + (size_t)Bn * Hn;

    int tch = 512;
    while (tch > 16) {
        size_t need = ((size_t)Bn * Tn * Hn + 2 * (size_t)Bn * Hn +
                       (size_t)Bn * tch * Gn) * sizeof(float);
        if (need <= ws_size) break;
        tch >>= 1;
    }
    int tlog = 31 - __builtin_clz((unsigned)tch);

    for (int l = 0; l < Ln; l++) {
        const float* A = (l == 0) ? x : hs;
        int K = (l == 0) ? Dn : Hn;
        const float* W = (l == 0) ? w_ih0 : (w_ih_rest + (size_t)(l - 1) * Gn * Hn);
        const float* whl = w_hh + (size_t)l * Gn * Hn;
        for (int c = 0; c < Tn / tch; c++) {
            dim3 gg(tch, 4);
            gemm_pre<<<gg, 256, 0, stream>>>(A, K, Tn * K, c * tch, tlog,
                                             W, b_ih + l * Gn, b_hh + l * Gn, pre);
            lstm_scan<<<Bn, 256, 0, stream>>>(pre, whl, hs, h_st, c_st,
                                              c * tch, tch, c == 0 ? 1 : 0);
        }
    }
    head_kernel<<<Bn, 256, 0, stream>>>(hs, w_attn, b_attn, w1, b1, w2, b2, out);
}

// Round 8
// 2083.604 us; speedup vs baseline: 1.2835x; 1.2835x over previous
//
#include <hip/hip_runtime.h>
#include <math.h>

#define Bn 128
#define Tn 512
#define Dn 32
#define Hn 128
#define Gn 512   // 4*H
#define Ln 3

// LDS-only barrier: does NOT drain vmcnt.
#define BAR_LDS() asm volatile("s_waitcnt lgkmcnt(0)\n\ts_barrier" ::: "memory")

// Opaque-origin pin: asm-produced values can't be rematerialized from loads.
#define KEEP4(q) asm volatile("" : "+v"(q.x), "+v"(q.y), "+v"(q.z), "+v"(q.w))

// ---------------------------------------------------------------------------
// GEMM: pre[M, 512] = A_chunk[M, K] * W[512, K]^T + (b_ih + b_hh)
// ---------------------------------------------------------------------------
__global__ __launch_bounds__(256) void gemm_pre(
    const float* __restrict__ A, int K, int rowStrideB, int t0, int tlog,
    const float* __restrict__ W,
    const float* __restrict__ bi, const float* __restrict__ bh,
    float* __restrict__ C)
{
    __shared__ __align__(16) float As[8][128];
    __shared__ __align__(16) float Bs[8][128];
    const int tid  = threadIdx.x;
    const int row0 = blockIdx.x * 128;
    const int col0 = blockIdx.y * 128;
    const int ty = tid >> 4, tx = tid & 15;
    const int lr = tid >> 1, lk = (tid & 1) * 4;
    const int tmask = (1 << tlog) - 1;

    float acc[8][8];
    #pragma unroll
    for (int i = 0; i < 8; i++)
        #pragma unroll
        for (int j = 0; j < 8; j++) acc[i][j] = 0.f;

    for (int k0 = 0; k0 < K; k0 += 8) {
        {
            int rg = row0 + lr;
            int b_idx = rg >> tlog;
            int tt = rg & tmask;
            const float* ap = A + (size_t)b_idx * rowStrideB +
                              (size_t)(t0 + tt) * K + (k0 + lk);
            float4 av = *(const float4*)ap;
            As[lk + 0][lr] = av.x; As[lk + 1][lr] = av.y;
            As[lk + 2][lr] = av.z; As[lk + 3][lr] = av.w;
            const float* wp = W + (size_t)(col0 + lr) * K + (k0 + lk);
            float4 wv = *(const float4*)wp;
            Bs[lk + 0][lr] = wv.x; Bs[lk + 1][lr] = wv.y;
            Bs[lk + 2][lr] = wv.z; Bs[lk + 3][lr] = wv.w;
        }
        __syncthreads();
        #pragma unroll
        for (int kk = 0; kk < 8; kk++) {
            float4 a0 = *(const float4*)&As[kk][ty * 8];
            float4 a1 = *(const float4*)&As[kk][ty * 8 + 4];
            float4 b0 = *(const float4*)&Bs[kk][tx * 8];
            float4 b1v = *(const float4*)&Bs[kk][tx * 8 + 4];
            float av[8] = {a0.x, a0.y, a0.z, a0.w, a1.x, a1.y, a1.z, a1.w};
            float bv[8] = {b0.x, b0.y, b0.z, b0.w, b1v.x, b1v.y, b1v.z, b1v.w};
            #pragma unroll
            for (int i = 0; i < 8; i++)
                #pragma unroll
                for (int j = 0; j < 8; j++) acc[i][j] += av[i] * bv[j];
        }
        __syncthreads();
    }
    #pragma unroll
    for (int i = 0; i < 8; i++) {
        int r = row0 + ty * 8 + i;
        #pragma unroll
        for (int j = 0; j < 8; j += 4) {
            int g = col0 + tx * 8 + j;
            float4 o;
            o.x = acc[i][j + 0] + bi[g + 0] + bh[g + 0];
            o.y = acc[i][j + 1] + bi[g + 1] + bh[g + 1];
            o.z = acc[i][j + 2] + bi[g + 2] + bh[g + 2];
            o.w = acc[i][j + 3] + bi[g + 3] + bh[g + 3];
            *(float4*)&C[(size_t)r * Gn + g] = o;
        }
    }
}

// ---------------------------------------------------------------------------
// LSTM scan v4. 1024 threads/block, one block per batch item.
// Thread (u, kq): unit u = tid&127, k-eighth kq = tid>>7 (uniform per wave).
// Holds w_hh[i_u|f_u|g_u|o_u][16kq..16kq+16) = 16 float4 (KEEP4-pinned,
// ~64 VGPRs -- the amount R7 proved the allocator will hold). Each readlane
// broadcast feeds 4 FMAs. k-partials reduced via LDS psum[8][128] float4;
// kq=0 thread has all 4 gate preacts locally -> update with no exchange.
// ---------------------------------------------------------------------------
__device__ __forceinline__ float bcast(float v, int l) {
    return __int_as_float(__builtin_amdgcn_readlane(__float_as_int(v), l));
}
__device__ __forceinline__ float sigm(float x) {
    return __builtin_amdgcn_rcpf(1.f + __expf(-x));
}
__device__ __forceinline__ float tanh_fast(float x) {
    return 1.f - 2.f * __builtin_amdgcn_rcpf(1.f + __expf(2.f * x));
}

// 4 k-steps: 4 broadcasts, each feeding the 4 gate accumulators.
#define MACQ(j4, qi, qf, qg, qo)                                   \
    {                                                              \
        float s0 = bcast(hx, kbase + (j4) + 0);                    \
        float s1 = bcast(hx, kbase + (j4) + 1);                    \
        float s2 = bcast(hx, kbase + (j4) + 2);                    \
        float s3 = bcast(hx, kbase + (j4) + 3);                    \
        aI = fmaf(s0, qi.x, aI); aF = fmaf(s0, qf.x, aF);          \
        aG = fmaf(s0, qg.x, aG); aO = fmaf(s0, qo.x, aO);          \
        aI = fmaf(s1, qi.y, aI); aF = fmaf(s1, qf.y, aF);          \
        aG = fmaf(s1, qg.y, aG); aO = fmaf(s1, qo.y, aO);          \
        aI = fmaf(s2, qi.z, aI); aF = fmaf(s2, qf.z, aF);          \
        aG = fmaf(s2, qg.z, aG); aO = fmaf(s2, qo.z, aO);          \
        aI = fmaf(s3, qi.w, aI); aF = fmaf(s3, qf.w, aF);          \
        aG = fmaf(s3, qg.w, aG); aO = fmaf(s3, qo.w, aO);          \
    }

__global__ __launch_bounds__(1024)
__attribute__((amdgpu_waves_per_eu(4, 4)))
void lstm_scan(
    const float* __restrict__ pre,     // [B*TCH, 512]
    const float* __restrict__ w_hh,    // [512, 128] (this layer)
    float* __restrict__ hs,            // [B, T, H] layer output
    float* __restrict__ h_state, float* __restrict__ c_state,
    int t0, int TCH, int first)
{
    const int b     = blockIdx.x;
    const int tid   = threadIdx.x;
    const int lane  = tid & 63;
    const int u     = tid & 127;        // hidden unit
    const int kq    = tid >> 7;         // k-eighth, uniform per wave
    const int kbase = (kq & 3) * 16;    // readlane base within hx
    const int hoff  = ((kq >> 2) << 6) + lane;   // h_sh slot this lane caches

    __shared__ __align__(16) float4 psum[8][Hn];   // [kq][u], kq=1..7 used
    __shared__ __align__(16) float  h_sh[Hn];

    // --- weights: 4 gate rows x 16 k = 16 float4, pinned ---
    const float4* pI = (const float4*)(w_hh + (size_t)(0 * Hn + u) * Hn + kq * 16);
    const float4* pF = (const float4*)(w_hh + (size_t)(1 * Hn + u) * Hn + kq * 16);
    const float4* pG = (const float4*)(w_hh + (size_t)(2 * Hn + u) * Hn + kq * 16);
    const float4* pO = (const float4*)(w_hh + (size_t)(3 * Hn + u) * Hn + kq * 16);
    float4 qi0 = pI[0], qi1 = pI[1], qi2 = pI[2], qi3 = pI[3];
    float4 qf0 = pF[0], qf1 = pF[1], qf2 = pF[2], qf3 = pF[3];
    float4 qg0 = pG[0], qg1 = pG[1], qg2 = pG[2], qg3 = pG[3];
    float4 qo0 = pO[0], qo1 = pO[1], qo2 = pO[2], qo3 = pO[3];
    KEEP4(qi0); KEEP4(qi1); KEEP4(qi2); KEEP4(qi3);
    KEEP4(qf0); KEEP4(qf1); KEEP4(qf2); KEEP4(qf3);
    KEEP4(qg0); KEEP4(qg1); KEEP4(qg2); KEEP4(qg3);
    KEEP4(qo0); KEEP4(qo1); KEEP4(qo2); KEEP4(qo3);

    float cr = 0.f;
    if (tid < Hn) {
        float hv = 0.f;
        if (!first) {
            hv = h_state[b * Hn + tid];
            cr = c_state[b * Hn + tid];
        }
        h_sh[tid] = hv;
    }
    __syncthreads();

    // pre pointers: only waves 0,1 (kq==0) touch pre
    const float* ppI = pre + (size_t)b * TCH * Gn + u;
    const float* ppF = ppI + Hn;
    const float* ppG = ppI + 2 * Hn;
    const float* ppO = ppI + 3 * Hn;
    float* hsb = hs + ((size_t)b * Tn + t0) * Hn;

    float pI0 = 0.f, pF0 = 0.f, pG0 = 0.f, pO0 = 0.f;
    float pI1 = 0.f, pF1 = 0.f, pG1 = 0.f, pO1 = 0.f;
    if (kq == 0) {
        pI0 = ppI[0]; pF0 = ppF[0]; pG0 = ppG[0]; pO0 = ppO[0];
        if (TCH > 1) { pI1 = ppI[Gn]; pF1 = ppF[Gn]; pG1 = ppG[Gn]; pO1 = ppO[Gn]; }
        else         { pI1 = pI0; pF1 = pF0; pG1 = pG0; pO1 = pO0; }
    }

    float hlast = 0.f;
    for (int t = 0; t < TCH; t++) {
        float hx = h_sh[hoff];

        float pvI = pI0, pvF = pF0, pvG = pG0, pvO = pO0;
        pI0 = pI1; pF0 = pF1; pG0 = pG1; pO0 = pO1;
        if (kq == 0) {
            int tn = (t + 2 < TCH) ? (t + 2) : (TCH - 1);
            size_t o = (size_t)tn * Gn;
            pI1 = ppI[o]; pF1 = ppF[o]; pG1 = ppG[o]; pO1 = ppO[o];
        }

        float aI = 0.f, aF = 0.f, aG = 0.f, aO = 0.f;
        MACQ(0,  qi0, qf0, qg0, qo0)
        MACQ(4,  qi1, qf1, qg1, qo1)
        MACQ(8,  qi2, qf2, qg2, qo2)
        MACQ(12, qi3, qf3, qg3, qo3)

        if (kq != 0) psum[kq][u] = make_float4(aI, aF, aG, aO);
        BAR_LDS();

        if (tid < Hn) {                 // waves 0,1: full reduction + update
            float4 s1 = psum[1][u], s2 = psum[2][u], s3 = psum[3][u];
            float4 s4 = psum[4][u], s5 = psum[5][u], s6 = psum[6][u];
            float4 s7 = psum[7][u];
            float gi = aI + pvI + ((s1.x + s2.x) + (s3.x + s4.x)) + ((s5.x + s6.x) + s7.x);
            float gf = aF + pvF + ((s1.y + s2.y) + (s3.y + s4.y)) + ((s5.y + s6.y) + s7.y);
            float gg = aG + pvG + ((s1.z + s2.z) + (s3.z + s4.z)) + ((s5.z + s6.z) + s7.z);
            float go = aO + pvO + ((s1.w + s2.w) + (s3.w + s4.w)) + ((s5.w + s6.w) + s7.w);
            float iv = sigm(gi);
            float fv = sigm(gf);
            float gv = tanh_fast(gg);
            float ov = sigm(go);
            cr = fv * cr + iv * gv;
            float hnew = ov * tanh_fast(cr);
            hlast = hnew;
            h_sh[u] = hnew;
            hsb[(size_t)t * Hn + u] = hnew;   // store stays in flight
        }
        BAR_LDS();
    }

    if (tid < Hn) {
        h_state[b * Hn + u] = hlast;
        c_state[b * Hn + u] = cr;
    }
}

// ---------------------------------------------------------------------------
// Attention pooling + MLP head. One block per batch item, 256 threads.
// ---------------------------------------------------------------------------
__global__ __launch_bounds__(256) void head_kernel(
    const float* __restrict__ hs,
    const float* __restrict__ w_attn, const float* __restrict__ b_attn,
    const float* __restrict__ w1, const float* __restrict__ b1,
    const float* __restrict__ w2, const float* __restrict__ b2,
    float* __restrict__ out)
{
    const int b = blockIdx.x;
    const int tid = threadIdx.x;
    __shared__ __align__(16) float wa_sh[Hn];
    __shared__ __align__(16) float sc[Tn];
    __shared__ __align__(16) float red[256];
    __shared__ __align__(16) float ctx_sh[Hn];
    __shared__ __align__(16) float h1_sh[64];

    if (tid < Hn) wa_sh[tid] = w_attn[tid];
    __syncthreads();

    const float* hb = hs + (size_t)b * Tn * Hn;

    for (int t = tid; t < Tn; t += 256) {
        const float4* hv = (const float4*)(hb + (size_t)t * Hn);
        const float4* wvv = (const float4*)wa_sh;
        float s = 0.f;
        #pragma unroll
        for (int k = 0; k < 32; k++) {
            float4 h4 = hv[k], w4 = wvv[k];
            s += h4.x * w4.x + h4.y * w4.y + h4.z * w4.z + h4.w * w4.w;
        }
        sc[t] = s + b_attn[0];
    }
    __syncthreads();

    float m = fmaxf(sc[tid], sc[tid + 256]);
    red[tid] = m; __syncthreads();
    for (int s_ = 128; s_ > 0; s_ >>= 1) {
        if (tid < s_) red[tid] = fmaxf(red[tid], red[tid + s_]);
        __syncthreads();
    }
    float mx = red[0];
    __syncthreads();
    float e0 = __expf(sc[tid] - mx), e1 = __expf(sc[tid + 256] - mx);
    sc[tid] = e0; sc[tid + 256] = e1;
    red[tid] = e0 + e1; __syncthreads();
    for (int s_ = 128; s_ > 0; s_ >>= 1) {
        if (tid < s_) red[tid] += red[tid + s_];
        __syncthreads();
    }
    float inv = 1.f / red[0];
    __syncthreads();

    {
        int jj = tid & 127, half = tid >> 7;
        float a = 0.f;
        for (int t = half * 256; t < half * 256 + 256; t++)
            a += sc[t] * hb[(size_t)t * Hn + jj];
        red[tid] = a;
        __syncthreads();
        if (tid < Hn) ctx_sh[tid] = (red[tid] + red[tid + Hn]) * inv;
        __syncthreads();
    }

    if (tid < 64) {
        const float4* wvv = (const float4*)(w1 + (size_t)tid * Hn);
        const float4* cv = (const float4*)ctx_sh;
        float s = 0.f;
        #pragma unroll
        for (int k = 0; k < 32; k++) {
            float4 a = wvv[k], c = cv[k];
            s += a.x * c.x + a.y * c.y + a.z * c.z + a.w * c.w;
        }
        h1_sh[tid] = fmaxf(s + b1[tid], 0.f);
    }
    __syncthreads();

    if (tid < 4) {
        float s = 0.f;
        const float* wvv = w2 + tid * 64;
        #pragma unroll
        for (int k = 0; k < 64; k++) s += wvv[k] * h1_sh[k];
        out[b * 4 + tid] = s + b2[tid];
    }
}

// ---------------------------------------------------------------------------
extern "C" void kernel_launch(void* const* d_in, const int* in_sizes, int n_in,
                              void* d_out, int out_size, void* d_ws, size_t ws_size,
                              hipStream_t stream)
{
    const float* x        = (const float*)d_in[0];
    const float* w_ih0    = (const float*)d_in[1];
    const float* w_ih_rest= (const float*)d_in[2];
    const float* w_hh     = (const float*)d_in[3];
    const float* b_ih     = (const float*)d_in[4];
    const float* b_hh     = (const float*)d_in[5];
    const float* w_attn   = (const float*)d_in[6];
    const float* b_attn   = (const float*)d_in[7];
    const float* w1       = (const float*)d_in[8];
    const float* b1       = (const float*)d_in[9];
    const float* w2       = (const float*)d_in[10];
    const float* b2       = (const float*)d_in[11];
    float* out = (float*)d_out;

    float* ws   = (float*)d_ws;
    float* hs   = ws;
    float* h_st = hs + (size_t)Bn * Tn * Hn;
    float* c_st = h_st + (size_t)Bn * Hn;
    float* pre  = c_st + (size_t)Bn * Hn;

    int tch = 512;
    while (tch > 16) {
        size_t need = ((size_t)Bn * Tn * Hn + 2 * (size_t)Bn * Hn +
                       (size_t)Bn * tch * Gn) * sizeof(float);
        if (need <= ws_size) break;
        tch >>= 1;
    }
    int tlog = 31 - __builtin_clz((unsigned)tch);

    for (int l = 0; l < Ln; l++) {
        const float* A = (l == 0) ? x : hs;
        int K = (l == 0) ? Dn : Hn;
        const float* W = (l == 0) ? w_ih0 : (w_ih_rest + (size_t)(l - 1) * Gn * Hn);
        const float* whl = w_hh + (size_t)l * Gn * Hn;
        for (int c = 0; c < Tn / tch; c++) {
            dim3 gg(tch, 4);
            gemm_pre<<<gg, 256, 0, stream>>>(A, K, Tn * K, c * tch, tlog,
                                             W, b_ih + l * Gn, b_hh + l * Gn, pre);
            lstm_scan<<<Bn, 1024, 0, stream>>>(pre, whl, hs, h_st, c_st,
                                               c * tch, tch, c == 0 ? 1 : 0);
        }
    }
    head_kernel<<<Bn, 256, 0, stream>>>(hs, w_attn, b_attn, w1, b1, w2, b2, out);
}

// Round 9
// 1454.373 us; speedup vs baseline: 1.8387x; 1.4326x over previous
//
#include <hip/hip_runtime.h>
#include <math.h>

#define Bn 128
#define Tn 512
#define Dn 32
#define Hn 128
#define Gn 512   // 4*H
#define Ln 3

// LDS-only barrier: does NOT drain vmcnt.
#define BAR_LDS() asm volatile("s_waitcnt lgkmcnt(0)\n\ts_barrier" ::: "memory")

typedef _Float16 h2 __attribute__((ext_vector_type(2)));

__device__ __forceinline__ float dot2(h2 a, h2 b, float c) {
    return __builtin_amdgcn_fdot2(a, b, c, false);
}
__device__ __forceinline__ h2 pkh(float a, float b) {
    h2 r; r.x = (_Float16)a; r.y = (_Float16)b; return r;
}
__device__ __forceinline__ h2 bcast2(h2 v, int l) {
    int i = __builtin_amdgcn_readlane(__builtin_bit_cast(int, v), l);
    return __builtin_bit_cast(h2, i);
}
__device__ __forceinline__ float sigm(float x) {
    return __builtin_amdgcn_rcpf(1.f + __expf(-x));
}
__device__ __forceinline__ float tanh_fast(float x) {
    return 1.f - 2.f * __builtin_amdgcn_rcpf(1.f + __expf(2.f * x));
}

#define KEEPH(x) asm volatile("" : "+v"(x))
#define DECL16(P, R) \
  h2 P##0=pkh(R[0],R[1]),   P##1=pkh(R[2],R[3]),   P##2=pkh(R[4],R[5]),   P##3=pkh(R[6],R[7]),   \
     P##4=pkh(R[8],R[9]),   P##5=pkh(R[10],R[11]), P##6=pkh(R[12],R[13]), P##7=pkh(R[14],R[15]), \
     P##8=pkh(R[16],R[17]), P##9=pkh(R[18],R[19]), P##10=pkh(R[20],R[21]),P##11=pkh(R[22],R[23]),\
     P##12=pkh(R[24],R[25]),P##13=pkh(R[26],R[27]),P##14=pkh(R[28],R[29]),P##15=pkh(R[30],R[31]);
#define KEEP16(P) \
  KEEPH(P##0); KEEPH(P##1); KEEPH(P##2); KEEPH(P##3); KEEPH(P##4); KEEPH(P##5); \
  KEEPH(P##6); KEEPH(P##7); KEEPH(P##8); KEEPH(P##9); KEEPH(P##10); KEEPH(P##11); \
  KEEPH(P##12); KEEPH(P##13); KEEPH(P##14); KEEPH(P##15);

// 1 broadcast pair feeds 4 dot2 (i,f,g,o share it).
#define DOT4(j) { h2 s = bcast2(hx, j);      \
    aI = dot2(s, wi##j, aI);                 \
    aF = dot2(s, wf##j, aF);                 \
    aG = dot2(s, wg##j, aG);                 \
    aO = dot2(s, wo##j, aO); }

// ---------------------------------------------------------------------------
// GEMM: pre[M, 512] = A_chunk[M, K] * W[512, K]^T + (b_ih + b_hh)
// ---------------------------------------------------------------------------
__global__ __launch_bounds__(256) void gemm_pre(
    const float* __restrict__ A, int K, int rowStrideB, int t0, int tlog,
    const float* __restrict__ W,
    const float* __restrict__ bi, const float* __restrict__ bh,
    float* __restrict__ C)
{
    __shared__ __align__(16) float As[8][128];
    __shared__ __align__(16) float Bs[8][128];
    const int tid  = threadIdx.x;
    const int row0 = blockIdx.x * 128;
    const int col0 = blockIdx.y * 128;
    const int ty = tid >> 4, tx = tid & 15;
    const int lr = tid >> 1, lk = (tid & 1) * 4;
    const int tmask = (1 << tlog) - 1;

    float acc[8][8];
    #pragma unroll
    for (int i = 0; i < 8; i++)
        #pragma unroll
        for (int j = 0; j < 8; j++) acc[i][j] = 0.f;

    for (int k0 = 0; k0 < K; k0 += 8) {
        {
            int rg = row0 + lr;
            int b_idx = rg >> tlog;
            int tt = rg & tmask;
            const float* ap = A + (size_t)b_idx * rowStrideB +
                              (size_t)(t0 + tt) * K + (k0 + lk);
            float4 av = *(const float4*)ap;
            As[lk + 0][lr] = av.x; As[lk + 1][lr] = av.y;
            As[lk + 2][lr] = av.z; As[lk + 3][lr] = av.w;
            const float* wp = W + (size_t)(col0 + lr) * K + (k0 + lk);
            float4 wv = *(const float4*)wp;
            Bs[lk + 0][lr] = wv.x; Bs[lk + 1][lr] = wv.y;
            Bs[lk + 2][lr] = wv.z; Bs[lk + 3][lr] = wv.w;
        }
        __syncthreads();
        #pragma unroll
        for (int kk = 0; kk < 8; kk++) {
            float4 a0 = *(const float4*)&As[kk][ty * 8];
            float4 a1 = *(const float4*)&As[kk][ty * 8 + 4];
            float4 b0 = *(const float4*)&Bs[kk][tx * 8];
            float4 b1v = *(const float4*)&Bs[kk][tx * 8 + 4];
            float av[8] = {a0.x, a0.y, a0.z, a0.w, a1.x, a1.y, a1.z, a1.w};
            float bv[8] = {b0.x, b0.y, b0.z, b0.w, b1v.x, b1v.y, b1v.z, b1v.w};
            #pragma unroll
            for (int i = 0; i < 8; i++)
                #pragma unroll
                for (int j = 0; j < 8; j++) acc[i][j] += av[i] * bv[j];
        }
        __syncthreads();
    }
    #pragma unroll
    for (int i = 0; i < 8; i++) {
        int r = row0 + ty * 8 + i;
        #pragma unroll
        for (int j = 0; j < 8; j += 4) {
            int g = col0 + tx * 8 + j;
            float4 o;
            o.x = acc[i][j + 0] + bi[g + 0] + bh[g + 0];
            o.y = acc[i][j + 1] + bi[g + 1] + bh[g + 1];
            o.z = acc[i][j + 2] + bi[g + 2] + bh[g + 2];
            o.w = acc[i][j + 3] + bi[g + 3] + bh[g + 3];
            *(float4*)&C[(size_t)r * Gn + g] = o;
        }
    }
}

// ---------------------------------------------------------------------------
// LSTM scan v5. 512 threads/block (8 waves), one block per batch item.
// Thread (u = tid&127, kq = tid>>7 in [0,4)): gates i,f,g,o of unit u over
// k in [32kq, 32kq+32), weights as 64 packed half2 VGPRs, MAC via
// v_dot2_f32_f16 (exact fp32 accumulate). Recurrent h carried as half2 in
// LDS; pre / c / hs output stay fp32. kq=3 waves own pre-prefetch (folded
// into psum[3]); kq=0 waves (tid<128) own the reduction + c/h update.
// ---------------------------------------------------------------------------
__global__ __launch_bounds__(512)
__attribute__((amdgpu_waves_per_eu(2, 2)))
void lstm_scan(
    const float* __restrict__ pre,     // [B*TCH, 512]
    const float* __restrict__ w_hh,    // [512, 128] (this layer)
    float* __restrict__ hs,            // [B, T, H] layer output (fp32)
    float* __restrict__ h_state, float* __restrict__ c_state,
    int t0, int TCH, int first)
{
    const int b    = blockIdx.x;
    const int tid  = threadIdx.x;
    const int lane = tid & 63;
    const int u    = tid & 127;        // hidden unit
    const int kq   = tid >> 7;         // k-quarter, wave-uniform

    __shared__ h2 h2_sh[Hn / 2];                 // h as 64 packed pairs
    __shared__ __align__(16) float4 psum[4][Hn]; // slots 1..3 used

    // --- weights: 4 gate rows x 32 k = 16 half2 per gate ---
    const float* rI = w_hh + (size_t)(0 * Hn + u) * Hn + kq * 32;
    const float* rF = w_hh + (size_t)(1 * Hn + u) * Hn + kq * 32;
    const float* rG = w_hh + (size_t)(2 * Hn + u) * Hn + kq * 32;
    const float* rO = w_hh + (size_t)(3 * Hn + u) * Hn + kq * 32;
    DECL16(wi, rI) DECL16(wf, rF) DECL16(wg, rG) DECL16(wo, rO)
    KEEP16(wi) KEEP16(wf) KEEP16(wg) KEEP16(wo)

    float cr = 0.f;
    if (tid < Hn && !first) cr = c_state[b * Hn + tid];
    if (tid < Hn / 2) {
        h2 hv = pkh(0.f, 0.f);
        if (!first) hv = pkh(h_state[b * Hn + 2 * tid],
                             h_state[b * Hn + 2 * tid + 1]);
        h2_sh[tid] = hv;
    }
    __syncthreads();

    // pre pointers: only kq==3 waves touch pre
    const float* ppI = pre + (size_t)b * TCH * Gn + u;
    const float* ppF = ppI + Hn;
    const float* ppG = ppI + 2 * Hn;
    const float* ppO = ppI + 3 * Hn;
    float* hsb = hs + ((size_t)b * Tn + t0) * Hn;

    float pI0 = 0.f, pF0 = 0.f, pG0 = 0.f, pO0 = 0.f;
    float pI1 = 0.f, pF1 = 0.f, pG1 = 0.f, pO1 = 0.f;
    if (kq == 3) {
        pI0 = ppI[0]; pF0 = ppF[0]; pG0 = ppG[0]; pO0 = ppO[0];
        if (TCH > 1) { pI1 = ppI[Gn]; pF1 = ppF[Gn]; pG1 = ppG[Gn]; pO1 = ppO[Gn]; }
        else         { pI1 = pI0; pF1 = pF0; pG1 = pG0; pO1 = pO0; }
    }

    const int hslot = kq * 16 + (lane & 15);   // this lane's h-pair cache

    float hlast = 0.f;
    for (int t = 0; t < TCH; t++) {
        h2 hx = h2_sh[hslot];

        float pvI = pI0, pvF = pF0, pvG = pG0, pvO = pO0;
        pI0 = pI1; pF0 = pF1; pG0 = pG1; pO0 = pO1;
        if (kq == 3) {
            int tn = (t + 2 < TCH) ? (t + 2) : (TCH - 1);
            size_t o = (size_t)tn * Gn;
            pI1 = ppI[o]; pF1 = ppF[o]; pG1 = ppG[o]; pO1 = ppO[o];
        }

        float aI = 0.f, aF = 0.f, aG = 0.f, aO = 0.f;
        DOT4(0)  DOT4(1)  DOT4(2)  DOT4(3)
        DOT4(4)  DOT4(5)  DOT4(6)  DOT4(7)
        DOT4(8)  DOT4(9)  DOT4(10) DOT4(11)
        DOT4(12) DOT4(13) DOT4(14) DOT4(15)

        if (kq == 3)
            psum[3][u] = make_float4(aI + pvI, aF + pvF, aG + pvG, aO + pvO);
        else if (kq != 0)
            psum[kq][u] = make_float4(aI, aF, aG, aO);
        BAR_LDS();

        if (tid < Hn) {                 // kq==0: reduce + update
            float4 s1 = psum[1][u], s2 = psum[2][u], s3 = psum[3][u];
            float gi = (aI + s1.x) + (s2.x + s3.x);
            float gf = (aF + s1.y) + (s2.y + s3.y);
            float gg = (aG + s1.z) + (s2.z + s3.z);
            float go = (aO + s1.w) + (s2.w + s3.w);
            float iv = sigm(gi);
            float fv = sigm(gf);
            float gv = tanh_fast(gg);
            float ov = sigm(go);
            cr = fv * cr + iv * gv;
            float hnew = ov * tanh_fast(cr);
            hlast = hnew;
            ((_Float16*)h2_sh)[u] = (_Float16)hnew;   // b16 LDS write
            hsb[(size_t)t * Hn + u] = hnew;           // fp32 trajectory
        }
        BAR_LDS();
    }

    if (tid < Hn) {
        h_state[b * Hn + u] = hlast;
        c_state[b * Hn + u] = cr;
    }
}

// ---------------------------------------------------------------------------
// Attention pooling + MLP head. One block per batch item, 256 threads.
// ---------------------------------------------------------------------------
__global__ __launch_bounds__(256) void head_kernel(
    const float* __restrict__ hs,
    const float* __restrict__ w_attn, const float* __restrict__ b_attn,
    const float* __restrict__ w1, const float* __restrict__ b1,
    const float* __restrict__ w2, const float* __restrict__ b2,
    float* __restrict__ out)
{
    const int b = blockIdx.x;
    const int tid = threadIdx.x;
    __shared__ __align__(16) float wa_sh[Hn];
    __shared__ __align__(16) float sc[Tn];
    __shared__ __align__(16) float red[256];
    __shared__ __align__(16) float ctx_sh[Hn];
    __shared__ __align__(16) float h1_sh[64];

    if (tid < Hn) wa_sh[tid] = w_attn[tid];
    __syncthreads();

    const float* hb = hs + (size_t)b * Tn * Hn;

    for (int t = tid; t < Tn; t += 256) {
        const float4* hv = (const float4*)(hb + (size_t)t * Hn);
        const float4* wvv = (const float4*)wa_sh;
        float s = 0.f;
        #pragma unroll
        for (int k = 0; k < 32; k++) {
            float4 h4 = hv[k], w4 = wvv[k];
            s += h4.x * w4.x + h4.y * w4.y + h4.z * w4.z + h4.w * w4.w;
        }
        sc[t] = s + b_attn[0];
    }
    __syncthreads();

    float m = fmaxf(sc[tid], sc[tid + 256]);
    red[tid] = m; __syncthreads();
    for (int s_ = 128; s_ > 0; s_ >>= 1) {
        if (tid < s_) red[tid] = fmaxf(red[tid], red[tid + s_]);
        __syncthreads();
    }
    float mx = red[0];
    __syncthreads();
    float e0 = __expf(sc[tid] - mx), e1 = __expf(sc[tid + 256] - mx);
    sc[tid] = e0; sc[tid + 256] = e1;
    red[tid] = e0 + e1; __syncthreads();
    for (int s_ = 128; s_ > 0; s_ >>= 1) {
        if (tid < s_) red[tid] += red[tid + s_];
        __syncthreads();
    }
    float inv = 1.f / red[0];
    __syncthreads();

    {
        int jj = tid & 127, half = tid >> 7;
        float a = 0.f;
        for (int t = half * 256; t < half * 256 + 256; t++)
            a += sc[t] * hb[(size_t)t * Hn + jj];
        red[tid] = a;
        __syncthreads();
        if (tid < Hn) ctx_sh[tid] = (red[tid] + red[tid + Hn]) * inv;
        __syncthreads();
    }

    if (tid < 64) {
        const float4* wvv = (const float4*)(w1 + (size_t)tid * Hn);
        const float4* cv = (const float4*)ctx_sh;
        float s = 0.f;
        #pragma unroll
        for (int k = 0; k < 32; k++) {
            float4 a = wvv[k], c = cv[k];
            s += a.x * c.x + a.y * c.y + a.z * c.z + a.w * c.w;
        }
        h1_sh[tid] = fmaxf(s + b1[tid], 0.f);
    }
    __syncthreads();

    if (tid < 4) {
        float s = 0.f;
        const float* wvv = w2 + tid * 64;
        #pragma unroll
        for (int k = 0; k < 64; k++) s += wvv[k] * h1_sh[k];
        out[b * 4 + tid] = s + b2[tid];
    }
}

// ---------------------------------------------------------------------------
extern "C" void kernel_launch(void* const* d_in, const int* in_sizes, int n_in,
                              void* d_out, int out_size, void* d_ws, size_t ws_size,
                              hipStream_t stream)
{
    const float* x        = (const float*)d_in[0];
    const float* w_ih0    = (const float*)d_in[1];
    const float* w_ih_rest= (const float*)d_in[2];
    const float* w_hh     = (const float*)d_in[3];
    const float* b_ih     = (const float*)d_in[4];
    const float* b_hh     = (const float*)d_in[5];
    const float* w_attn   = (const float*)d_in[6];
    const float* b_attn   = (const float*)d_in[7];
    const float* w1       = (const float*)d_in[8];
    const float* b1       = (const float*)d_in[9];
    const float* w2       = (const float*)d_in[10];
    const float* b2       = (const float*)d_in[11];
    float* out = (float*)d_out;

    float* ws   = (float*)d_ws;
    float* hs   = ws;
    float* h_st = hs + (size_t)Bn * Tn * Hn;
    float* c_st = h_st + (size_t)Bn * Hn;
    float* pre  = c_st + (size_t)Bn * Hn;

    int tch = 512;
    while (tch > 16) {
        size_t need = ((size_t)Bn * Tn * Hn + 2 * (size_t)Bn * Hn +
                       (size_t)Bn * tch * Gn) * sizeof(float);
        if (need <= ws_size) break;
        tch >>= 1;
    }
    int tlog = 31 - __builtin_clz((unsigned)tch);

    for (int l = 0; l < Ln; l++) {
        const float* A = (l == 0) ? x : hs;
        int K = (l == 0) ? Dn : Hn;
        const float* W = (l == 0) ? w_ih0 : (w_ih_rest + (size_t)(l - 1) * Gn * Hn);
        const float* whl = w_hh + (size_t)l * Gn * Hn;
        for (int c = 0; c < Tn / tch; c++) {
            dim3 gg(tch, 4);
            gemm_pre<<<gg, 256, 0, stream>>>(A, K, Tn * K, c * tch, tlog,
                                             W, b_ih + l * Gn, b_hh + l * Gn, pre);
            lstm_scan<<<Bn, 512, 0, stream>>>(pre, whl, hs, h_st, c_st,
                                              c * tch, tch, c == 0 ? 1 : 0);
        }
    }
    head_kernel<<<Bn, 256, 0, stream>>>(hs, w_attn, b_attn, w1, b1, w2, b2, out);
}